// Round 2
// baseline (2251.517 us; speedup 1.0000x reference)
//
#include <hip/hip_runtime.h>

typedef __attribute__((ext_vector_type(8))) _Float16 f16x8;
typedef __attribute__((ext_vector_type(2))) _Float16 f16x2;
typedef __attribute__((ext_vector_type(4))) float f32x4;

// ---------------- workspace layout (bytes) ----------------
#define OFF_X1 0L
#define SZ_X1  (41L*128*128*64*2)
#define OFF_X2 (OFF_X1 + SZ_X1)
#define SZ_X2  (20L*128*128*64*2)
#define OFF_M1 (OFF_X2 + SZ_X2)
#define SZ_M1  (20L*128*128*4)
#define OFF_W0 (OFF_M1 + SZ_M1)
#define SZ_W0  (27L*64*128*2)
#define OFF_W1 (OFF_W0 + SZ_W0)
#define SZ_W1  (3L*64*64*2)
#define OFF_W2 (OFF_W1 + SZ_W1)
#define SZ_W2  (27L*64*64*2)
#define OFF_W3 (OFF_W2 + SZ_W2)
#define SZ_W3  (27L*64*64*2)
#define OFF_W4 (OFF_W3 + SZ_W3)
#define SZ_W4  (3L*64*64*2)

// ---------------- weight pre-transform: [CO][CI][T] f32 -> [T][CO][CI] f16 ----
__global__ void prep_w(const float* __restrict__ w, _Float16* __restrict__ o,
                       int CO, int CI, int T) {
    int i = blockIdx.x * 256 + threadIdx.x;
    int n = CO * CI * T;
    if (i >= n) return;
    int t  = i % T;
    int ci = (i / T) % CI;
    int co = i / (T * CI);
    o[((long)t * CO + co) * CI + ci] = (_Float16)w[i];
}

// ---------------- mask downsample ----------------
__global__ void prep_m1(const float* __restrict__ mask, float* __restrict__ m1) {
    int i = blockIdx.x * 256 + threadIdx.x;
    if (i >= 20 * 16384) return;
    int d1 = i >> 14;
    int rr = i & 16383;
    const float* p = mask + ((long)(2 * d1) << 14) + rr;
    float mx = fmaxf(p[0], fmaxf(p[16384], p[32768]));
    m1[i] = (mx > 0.5f) ? 1.0f : 0.0f;
}

// ---------------- submanifold 3x3x3 conv (SAME), masked output --------------
// Block: 256 threads (4 waves) = 2 output h-rows x 2 voxel-halves.
// LDS: single input row, 130 voxels x CIN f16, XOR-swizzled 16B chunks
// (chunk j stored at j ^ (slot&7)) -> conflict-free b128 frag reads, no pad.
// B fragments read directly from global (per-tap 8-16KB, L1-resident).
template<int CIN, bool FP32_IN>
__global__ __launch_bounds__(256, 4)
void subm_conv(const void* __restrict__ xin,
               const float* __restrict__ mrow,     // [D][128][128] (0/1-ish floats)
               const _Float16* __restrict__ wt,    // [27][64][CIN]
               _Float16* __restrict__ xout,        // [D][128][128][64]
               int D) {
    constexpr int NCH = CIN / 8;                   // 16B chunks per voxel
    constexpr int NK  = CIN / 32;                  // MFMA k-steps per tap
    __shared__ __align__(16) _Float16 lA[130 * CIN];

    const int h0 = blockIdx.x * 2;
    const int d  = blockIdx.y;
    const int tid = threadIdx.x;
    const int wv  = tid >> 6;          // wave 0..3
    const int lane = tid & 63;
    const int q = lane >> 4;
    const int r = lane & 15;
    const int hw = h0 + (wv >> 1);     // this wave's output row
    const int wh = wv & 1;             // voxel half (0: 0..63, 1: 64..127)

    f32x4 acc[4][4];
    #pragma unroll
    for (int mt = 0; mt < 4; ++mt)
        #pragma unroll
        for (int nt = 0; nt < 4; ++nt) {
            acc[mt][nt][0] = 0.f; acc[mt][nt][1] = 0.f;
            acc[mt][nt][2] = 0.f; acc[mt][nt][3] = 0.f;
        }

    const long CS = (long)D * 16384;   // fp32 channel stride (voxels)

    for (int kd = 0; kd < 3; ++kd) {
        int id = d + kd - 1;
        if ((unsigned)id >= (unsigned)D) continue;
        for (int ihh = 0; ihh < 4; ++ihh) {
            int ih = h0 - 1 + ihh;
            if ((unsigned)ih >= 128u) continue;
            __syncthreads();           // previous readers done before restage
            // halo slots 0 (iw=-1) and 129 (iw=128): zero
            if (tid < 2 * NCH) {
                int row = (tid < NCH) ? 0 : 129;
                int j = tid & (NCH - 1);
                f16x8 z = {};
                *(f16x8*)&lA[row * CIN + j * 8] = z;
            }
            if (FP32_IN) {
                const float* fsrc = (const float*)xin;
                long rb = ((long)id * 128 + ih) * 128;
                int wvx = tid >> 1, cq = tid & 1;
                float mval = (mrow[rb + wvx] > 0.5f) ? 1.0f : 0.0f;
                int slot = wvx + 1, sw = slot & 7;
                _Float16* dst = &lA[slot * CIN];
                const float* fp = fsrc + rb + wvx;
                #pragma unroll 4
                for (int p = 0; p < CIN / 4; ++p) {
                    int ci0 = 4 * p + 2 * cq;
                    float a = fp[(long)ci0 * CS] * mval;
                    float b = fp[(long)ci0 * CS + CS] * mval;
                    int pos = (((ci0 >> 3) ^ sw) << 3) + (ci0 & 7);
                    f16x2 pk; pk[0] = (_Float16)a; pk[1] = (_Float16)b;
                    *(f16x2*)&dst[pos] = pk;
                }
            } else {
                const _Float16* hsrc = (const _Float16*)xin +
                                       (((long)id * 128 + ih) * 128) * CIN;
                #pragma unroll
                for (int c = tid; c < 128 * NCH; c += 256) {
                    int v = c / NCH;
                    int j = c & (NCH - 1);
                    int slot = v + 1;
                    f16x8 val = *(const f16x8*)&hsrc[c * 8];
                    *(f16x8*)&lA[slot * CIN + ((j ^ (slot & 7)) << 3)] = val;
                }
            }
            __syncthreads();
            int kh = ih - hw + 1;              // wave-uniform
            if (kh < 0 || kh > 2) continue;    // barrier counts still match
            #pragma unroll
            for (int kw = 0; kw < 3; ++kw) {
                int tap = (kd * 3 + kh) * 3 + kw;
                const _Float16* wb = wt + (long)tap * 64 * CIN;
                #pragma unroll
                for (int kc = 0; kc < NK; ++kc) {
                    f16x8 af[4], bf[4];
                    #pragma unroll
                    for (int mt = 0; mt < 4; ++mt) {
                        int vl = wh * 64 + mt * 16 + r + kw;   // LDS slot
                        af[mt] = *(const f16x8*)&lA[vl * CIN +
                                   ((((kc << 2) + q) ^ (vl & 7)) << 3)];
                    }
                    #pragma unroll
                    for (int nt = 0; nt < 4; ++nt)
                        bf[nt] = *(const f16x8*)&wb[(nt * 16 + r) * CIN + kc * 32 + q * 8];
                    #pragma unroll
                    for (int mt = 0; mt < 4; ++mt)
                        #pragma unroll
                        for (int nt = 0; nt < 4; ++nt)
                            acc[mt][nt] = __builtin_amdgcn_mfma_f32_16x16x32_f16(
                                af[mt], bf[nt], acc[mt][nt], 0, 0, 0);
                }
            }
        }
    }
    // epilogue: relu * out-mask, store NDHWC f16
    long ob = (((long)d * 128 + hw) * 128) * 64;
    const float* mo = mrow + ((long)d * 128 + hw) * 128;
    #pragma unroll
    for (int mt = 0; mt < 4; ++mt) {
        #pragma unroll
        for (int i = 0; i < 4; ++i) {
            int v = wh * 64 + mt * 16 + q * 4 + i;
            float m = (mo[v] > 0.5f) ? 1.0f : 0.0f;
            #pragma unroll
            for (int nt = 0; nt < 4; ++nt) {
                float val = acc[mt][nt][i];
                val = val > 0.f ? val : 0.f;
                xout[ob + (long)v * 64 + nt * 16 + r] = (_Float16)(val * m);
            }
        }
    }
}

// ---------------- down1: k=(3,1,1) stride(2,1,1) VALID, relu ----------------
__global__ __launch_bounds__(128)
void down1_kernel(const _Float16* __restrict__ xin,  // X1 [41][128][128][64]
                  const _Float16* __restrict__ wt,   // [3][64][64]
                  _Float16* __restrict__ xout) {     // X2 [20][128][128][64]
    __shared__ __align__(16) _Float16 lB[3 * 64 * 72];
    const int bid = blockIdx.x;
    const int d1 = bid >> 7;
    const int h = bid & 127;
    const int tid = threadIdx.x;
    const int wv = tid >> 6;
    const int lane = tid & 63;
    const int q = lane >> 4;
    const int r = lane & 15;

    for (int c = tid; c < 3 * 64 * 8; c += 128) {
        int row = c >> 3;
        int part = c & 7;
        *(f16x8*)&lB[row * 72 + part * 8] = *(const f16x8*)&wt[row * 64 + part * 8];
    }
    __syncthreads();

    f32x4 acc[4][4];
    #pragma unroll
    for (int mt = 0; mt < 4; ++mt)
        #pragma unroll
        for (int nt = 0; nt < 4; ++nt) {
            acc[mt][nt][0] = 0.f; acc[mt][nt][1] = 0.f;
            acc[mt][nt][2] = 0.f; acc[mt][nt][3] = 0.f;
        }

    for (int kd = 0; kd < 3; ++kd) {
        long ib = (((long)(2 * d1 + kd) * 128 + h) * 128) * 64;
        #pragma unroll
        for (int kc = 0; kc < 2; ++kc) {
            f16x8 af[4], bf[4];
            #pragma unroll
            for (int mt = 0; mt < 4; ++mt)
                af[mt] = *(const f16x8*)&xin[ib + (long)(wv * 64 + mt * 16 + r) * 64 + kc * 32 + q * 8];
            #pragma unroll
            for (int nt = 0; nt < 4; ++nt)
                bf[nt] = *(const f16x8*)&lB[(kd * 64 + nt * 16 + r) * 72 + kc * 32 + q * 8];
            #pragma unroll
            for (int mt = 0; mt < 4; ++mt)
                #pragma unroll
                for (int nt = 0; nt < 4; ++nt)
                    acc[mt][nt] = __builtin_amdgcn_mfma_f32_16x16x32_f16(
                        af[mt], bf[nt], acc[mt][nt], 0, 0, 0);
        }
    }
    long ob = (((long)d1 * 128 + h) * 128) * 64;
    #pragma unroll
    for (int mt = 0; mt < 4; ++mt)
        #pragma unroll
        for (int i = 0; i < 4; ++i) {
            int v = wv * 64 + mt * 16 + q * 4 + i;
            #pragma unroll
            for (int nt = 0; nt < 4; ++nt) {
                float val = acc[mt][nt][i];
                xout[ob + (long)v * 64 + nt * 16 + r] = (_Float16)(val > 0.f ? val : 0.f);
            }
        }
}

// ---------------- down2: swapped operands -> coalesced NCDHW fp32 stores ----
__global__ __launch_bounds__(128)
void down2_kernel(const _Float16* __restrict__ xin,  // X4 [20][128][128][64]
                  const _Float16* __restrict__ wt,   // [3][64][64]
                  float* __restrict__ out) {         // [64][9][128][128]
    __shared__ __align__(16) _Float16 lB[3 * 64 * 72];
    const int bid = blockIdx.x;
    const int d2 = bid >> 7;
    const int h = bid & 127;
    const int tid = threadIdx.x;
    const int wv = tid >> 6;
    const int lane = tid & 63;
    const int q = lane >> 4;
    const int r = lane & 15;

    for (int c = tid; c < 3 * 64 * 8; c += 128) {
        int row = c >> 3;
        int part = c & 7;
        *(f16x8*)&lB[row * 72 + part * 8] = *(const f16x8*)&wt[row * 64 + part * 8];
    }
    __syncthreads();

    f32x4 acc[4][4];
    #pragma unroll
    for (int mt = 0; mt < 4; ++mt)
        #pragma unroll
        for (int nt = 0; nt < 4; ++nt) {
            acc[mt][nt][0] = 0.f; acc[mt][nt][1] = 0.f;
            acc[mt][nt][2] = 0.f; acc[mt][nt][3] = 0.f;
        }

    for (int kd = 0; kd < 3; ++kd) {
        long ib = (((long)(2 * d2 + kd) * 128 + h) * 128) * 64;
        #pragma unroll
        for (int kc = 0; kc < 2; ++kc) {
            f16x8 wf[4], xf[4];
            #pragma unroll
            for (int mt = 0; mt < 4; ++mt)
                wf[mt] = *(const f16x8*)&lB[(kd * 64 + mt * 16 + r) * 72 + kc * 32 + q * 8];
            #pragma unroll
            for (int nt = 0; nt < 4; ++nt)
                xf[nt] = *(const f16x8*)&xin[ib + (long)(wv * 64 + nt * 16 + r) * 64 + kc * 32 + q * 8];
            #pragma unroll
            for (int mt = 0; mt < 4; ++mt)
                #pragma unroll
                for (int nt = 0; nt < 4; ++nt)
                    acc[mt][nt] = __builtin_amdgcn_mfma_f32_16x16x32_f16(
                        wf[mt], xf[nt], acc[mt][nt], 0, 0, 0);
        }
    }
    #pragma unroll
    for (int mt = 0; mt < 4; ++mt)
        #pragma unroll
        for (int i = 0; i < 4; ++i) {
            int co = mt * 16 + q * 4 + i;
            #pragma unroll
            for (int nt = 0; nt < 4; ++nt) {
                int v = wv * 64 + nt * 16 + r;
                float val = acc[mt][nt][i];
                out[((long)co * 9 + d2) * 16384 + h * 128 + v] = (val > 0.f ? val : 0.f);
            }
        }
}

// ---------------- launcher ----------------
extern "C" void kernel_launch(void* const* d_in, const int* in_sizes, int n_in,
                              void* d_out, int out_size, void* d_ws, size_t ws_size,
                              hipStream_t stream) {
    (void)in_sizes; (void)n_in; (void)out_size; (void)ws_size;
    const float* feat = (const float*)d_in[0];
    const float* mask = (const float*)d_in[1];
    const float* w0 = (const float*)d_in[2];
    const float* w1 = (const float*)d_in[3];
    const float* w2 = (const float*)d_in[4];
    const float* w3 = (const float*)d_in[5];
    const float* w4 = (const float*)d_in[6];

    char* ws = (char*)d_ws;
    _Float16* X1  = (_Float16*)(ws + OFF_X1);
    _Float16* X2  = (_Float16*)(ws + OFF_X2);
    _Float16* X3  = (_Float16*)(ws + OFF_X1);   // reuse X1 region
    _Float16* X4  = (_Float16*)(ws + OFF_X2);   // reuse X2 region
    float*    M1  = (float*)(ws + OFF_M1);
    _Float16* W0t = (_Float16*)(ws + OFF_W0);
    _Float16* W1t = (_Float16*)(ws + OFF_W1);
    _Float16* W2t = (_Float16*)(ws + OFF_W2);
    _Float16* W3t = (_Float16*)(ws + OFF_W3);
    _Float16* W4t = (_Float16*)(ws + OFF_W4);

    prep_w<<<(27*64*128 + 255) / 256, 256, 0, stream>>>(w0, W0t, 64, 128, 27);
    prep_w<<<(3*64*64   + 255) / 256, 256, 0, stream>>>(w1, W1t, 64, 64, 3);
    prep_w<<<(27*64*64  + 255) / 256, 256, 0, stream>>>(w2, W2t, 64, 64, 27);
    prep_w<<<(27*64*64  + 255) / 256, 256, 0, stream>>>(w3, W3t, 64, 64, 27);
    prep_w<<<(3*64*64   + 255) / 256, 256, 0, stream>>>(w4, W4t, 64, 64, 3);
    prep_m1<<<(20*16384 + 255) / 256, 256, 0, stream>>>(mask, M1);

    // conv0: 128->64, 3x3x3 SAME, masked in & out (fp32 NCDHW in)
    subm_conv<128, true><<<dim3(64, 41), 256, 0, stream>>>(feat, mask, W0t, X1, 41);
    // down1
    down1_kernel<<<20 * 128, 128, 0, stream>>>(X1, W1t, X2);
    // subm1a / subm1b (f16 NDHWC in, mask M1)
    subm_conv<64, false><<<dim3(64, 20), 256, 0, stream>>>(X2, M1, W2t, X3, 20);
    subm_conv<64, false><<<dim3(64, 20), 256, 0, stream>>>(X3, M1, W3t, X4, 20);
    // down2 -> fp32 NCDHW output
    down2_kernel<<<9 * 128, 128, 0, stream>>>(X4, W4t, (float*)d_out);
}

// Round 3
// 1071.338 us; speedup vs baseline: 2.1016x; 2.1016x over previous
//
#include <hip/hip_runtime.h>

typedef __attribute__((ext_vector_type(8))) _Float16 f16x8;
typedef __attribute__((ext_vector_type(4))) float f32x4;

#define NVOX0 (41L*16384)
#define NVOX1 (20L*16384)

// ---------------- workspace layout (bytes) ----------------
// X0 [41][128][128][128] f16 (172MB) — dead after conv0; X2/X3/X4 overlay it.
#define OFF_X0 0L
#define SZ_X0  (NVOX0*128*2)
#define OFF_X2 0L                          // [20][...][64] f16, 42MB
#define SZ_X2  (NVOX1*64*2)
#define OFF_X3 SZ_X2                       // 42MB, after X2
#define OFF_X4 0L                          // overlays X2 (dead after subm1a)
#define OFF_X1 SZ_X0                       // [41][...][64] f16, 86MB (live across)
#define SZ_X1  (NVOX0*64*2)
#define OFF_M1 (OFF_X1 + SZ_X1)
#define SZ_M1  (NVOX1*4)
#define OFF_W0 (OFF_M1 + SZ_M1)
#define SZ_W0  (27L*64*128*2)
#define OFF_W1 (OFF_W0 + SZ_W0)
#define SZ_W1  (3L*64*64*2)
#define OFF_W2 (OFF_W1 + SZ_W1)
#define SZ_W2  (27L*64*64*2)
#define OFF_W3 (OFF_W2 + SZ_W2)
#define SZ_W3  (27L*64*64*2)
#define OFF_W4 (OFF_W3 + SZ_W3)
#define SZ_W4  (3L*64*64*2)

// ---- weight to frag-major: [CO][CI][T] f32 -> [T][NK][4][64][8] f16 ----
// element (t,kc,nt,lane,e): co = nt*16+(lane&15), ci = kc*32+(lane>>4)*8+e
__global__ void prep_w_frag(const float* __restrict__ w, _Float16* __restrict__ o,
                            int CIN, int NK, int T) {
    int i = blockIdx.x * 256 + threadIdx.x;
    int n = T * NK * 2048;
    if (i >= n) return;
    int e = i & 7;
    int lane = (i >> 3) & 63;
    int nt = (i >> 9) & 3;
    int rest = i >> 11;
    int kc = rest % NK;
    int t = rest / NK;
    int co = nt * 16 + (lane & 15);
    int ci = kc * 32 + (lane >> 4) * 8 + e;
    o[i] = (_Float16)w[((long)co * CIN + ci) * T + t];
}

// ---- weight [CO][CI][T] f32 -> [T][CO][CI] f16 (for down1/down2) ----
__global__ void prep_w(const float* __restrict__ w, _Float16* __restrict__ o,
                       int CO, int CI, int T) {
    int i = blockIdx.x * 256 + threadIdx.x;
    int n = CO * CI * T;
    if (i >= n) return;
    int t  = i % T;
    int ci = (i / T) % CI;
    int co = i / (T * CI);
    o[((long)t * CO + co) * CI + ci] = (_Float16)w[i];
}

// ---- mask downsample ----
__global__ void prep_m1(const float* __restrict__ mask, float* __restrict__ m1) {
    int i = blockIdx.x * 256 + threadIdx.x;
    if (i >= (int)NVOX1) return;
    int d1 = i >> 14;
    int rr = i & 16383;
    const float* p = mask + ((long)(2 * d1) << 14) + rr;
    float mx = fmaxf(p[0], fmaxf(p[16384], p[32768]));
    m1[i] = (mx > 0.5f) ? 1.0f : 0.0f;
}

// ---- fp32 NCDHW -> f16 NDHWC with input mask folded in ----
__global__ __launch_bounds__(256)
void prep_x0(const float* __restrict__ feat, const float* __restrict__ mask,
             _Float16* __restrict__ x0) {
    long v = (long)blockIdx.x * 256 + threadIdx.x;
    if (v >= NVOX0) return;
    float m = (mask[v] > 0.5f) ? 1.0f : 0.0f;
    const float* fp = feat + v;
    _Float16* op = x0 + v * 128;
    #pragma unroll 2
    for (int ci0 = 0; ci0 < 128; ci0 += 8) {
        f16x8 pk;
        #pragma unroll
        for (int k = 0; k < 8; ++k)
            pk[k] = (_Float16)(fp[(long)(ci0 + k) * NVOX0] * m);
        *(f16x8*)&op[ci0] = pk;
    }
}

// ---------------- submanifold 3x3x3 conv (SAME), masked output --------------
// 128 threads = 2 waves, one output (d,h) row. lA-only LDS (XOR-swizzled 16B
// chunks: chunk j at j^(slot&7)). B frags from frag-major global (coalesced,
// L1/L2-resident). XCD swizzle: h-strips of 16 per XCD slot.
template<int CIN>
__global__ __launch_bounds__(128)
void subm_conv(const _Float16* __restrict__ xin,    // [D][128][128][CIN]
               const float* __restrict__ mrow,      // [D][128][128]
               const _Float16* __restrict__ wf,     // [27][NK][4][64][8]
               _Float16* __restrict__ xout,         // [D][128][128][64]
               int D) {
    constexpr int NCH = CIN / 8;
    constexpr int NK  = CIN / 32;
    __shared__ __align__(16) _Float16 lA[130 * CIN];

    const int bid = blockIdx.x;
    const int h = ((bid & 7) << 4) | ((bid >> 3) & 15);   // XCD-local h strip
    const int d = bid >> 7;
    const int tid = threadIdx.x;
    const int wh = tid >> 6;           // voxel half (0:0..63, 1:64..127)
    const int lane = tid & 63;
    const int q = lane >> 4;
    const int r = lane & 15;

    f32x4 acc[4][4];
    #pragma unroll
    for (int mt = 0; mt < 4; ++mt)
        #pragma unroll
        for (int nt = 0; nt < 4; ++nt) {
            acc[mt][nt][0] = 0.f; acc[mt][nt][1] = 0.f;
            acc[mt][nt][2] = 0.f; acc[mt][nt][3] = 0.f;
        }

    for (int kd = 0; kd < 3; ++kd) {
        int id = d + kd - 1;
        if ((unsigned)id >= (unsigned)D) continue;
        for (int kh = 0; kh < 3; ++kh) {
            int ih = h + kh - 1;
            if ((unsigned)ih >= 128u) continue;
            __syncthreads();               // prior readers done before restage
            // halo slots 0 (iw=-1), 129 (iw=128): zero (any chunk order ok)
            if (tid < 2 * NCH) {
                int slot = (tid < NCH) ? 0 : 129;
                int j = tid & (NCH - 1);
                f16x8 z = {};
                *(f16x8*)&lA[slot * CIN + j * 8] = z;
            }
            {
                const _Float16* src = xin + (((long)id * 128 + ih) * 128) * CIN;
                #pragma unroll
                for (int k = 0; k < NCH; ++k) {
                    int c = tid + k * 128;
                    int v = c / NCH;
                    int j = c & (NCH - 1);
                    int slot = v + 1;
                    f16x8 val = *(const f16x8*)&src[c * 8];
                    *(f16x8*)&lA[slot * CIN + ((j ^ (slot & 7)) << 3)] = val;
                }
            }
            __syncthreads();
            #pragma unroll
            for (int kw = 0; kw < 3; ++kw) {
                const _Float16* wb = wf + (long)((kd * 3 + kh) * 3 + kw) * NK * 2048;
                #pragma unroll
                for (int kc = 0; kc < NK; ++kc) {
                    f16x8 bf[4], af[4];
                    #pragma unroll
                    for (int nt = 0; nt < 4; ++nt)
                        bf[nt] = *(const f16x8*)&wb[((kc * 4 + nt) * 64 + lane) * 8];
                    #pragma unroll
                    for (int mt = 0; mt < 4; ++mt) {
                        int vl = wh * 64 + mt * 16 + r + kw;
                        af[mt] = *(const f16x8*)&lA[vl * CIN +
                                   ((((kc << 2) + q) ^ (vl & 7)) << 3)];
                    }
                    #pragma unroll
                    for (int mt = 0; mt < 4; ++mt)
                        #pragma unroll
                        for (int nt = 0; nt < 4; ++nt)
                            acc[mt][nt] = __builtin_amdgcn_mfma_f32_16x16x32_f16(
                                af[mt], bf[nt], acc[mt][nt], 0, 0, 0);
                }
            }
        }
    }
    // epilogue: relu * out-mask, store NDHWC f16
    long ob = (((long)d * 128 + h) * 128) * 64;
    const float* mo = mrow + ((long)d * 128 + h) * 128;
    #pragma unroll
    for (int mt = 0; mt < 4; ++mt) {
        #pragma unroll
        for (int i = 0; i < 4; ++i) {
            int v = wh * 64 + mt * 16 + q * 4 + i;
            float m = (mo[v] > 0.5f) ? 1.0f : 0.0f;
            #pragma unroll
            for (int nt = 0; nt < 4; ++nt) {
                float val = acc[mt][nt][i];
                val = val > 0.f ? val : 0.f;
                xout[ob + (long)v * 64 + nt * 16 + r] = (_Float16)(val * m);
            }
        }
    }
}

// ---------------- down1: k=(3,1,1) stride(2,1,1) VALID, relu ----------------
__global__ __launch_bounds__(128)
void down1_kernel(const _Float16* __restrict__ xin,  // X1 [41][128][128][64]
                  const _Float16* __restrict__ wt,   // [3][64][64]
                  _Float16* __restrict__ xout) {     // X2 [20][128][128][64]
    __shared__ __align__(16) _Float16 lB[3 * 64 * 72];
    const int bid = blockIdx.x;
    const int d1 = bid >> 7;
    const int h = bid & 127;
    const int tid = threadIdx.x;
    const int wv = tid >> 6;
    const int lane = tid & 63;
    const int q = lane >> 4;
    const int r = lane & 15;

    for (int c = tid; c < 3 * 64 * 8; c += 128) {
        int row = c >> 3;
        int part = c & 7;
        *(f16x8*)&lB[row * 72 + part * 8] = *(const f16x8*)&wt[row * 64 + part * 8];
    }
    __syncthreads();

    f32x4 acc[4][4];
    #pragma unroll
    for (int mt = 0; mt < 4; ++mt)
        #pragma unroll
        for (int nt = 0; nt < 4; ++nt) {
            acc[mt][nt][0] = 0.f; acc[mt][nt][1] = 0.f;
            acc[mt][nt][2] = 0.f; acc[mt][nt][3] = 0.f;
        }

    for (int kd = 0; kd < 3; ++kd) {
        long ib = (((long)(2 * d1 + kd) * 128 + h) * 128) * 64;
        #pragma unroll
        for (int kc = 0; kc < 2; ++kc) {
            f16x8 af[4], bf[4];
            #pragma unroll
            for (int mt = 0; mt < 4; ++mt)
                af[mt] = *(const f16x8*)&xin[ib + (long)(wv * 64 + mt * 16 + r) * 64 + kc * 32 + q * 8];
            #pragma unroll
            for (int nt = 0; nt < 4; ++nt)
                bf[nt] = *(const f16x8*)&lB[(kd * 64 + nt * 16 + r) * 72 + kc * 32 + q * 8];
            #pragma unroll
            for (int mt = 0; mt < 4; ++mt)
                #pragma unroll
                for (int nt = 0; nt < 4; ++nt)
                    acc[mt][nt] = __builtin_amdgcn_mfma_f32_16x16x32_f16(
                        af[mt], bf[nt], acc[mt][nt], 0, 0, 0);
        }
    }
    long ob = (((long)d1 * 128 + h) * 128) * 64;
    #pragma unroll
    for (int mt = 0; mt < 4; ++mt)
        #pragma unroll
        for (int i = 0; i < 4; ++i) {
            int v = wv * 64 + mt * 16 + q * 4 + i;
            #pragma unroll
            for (int nt = 0; nt < 4; ++nt) {
                float val = acc[mt][nt][i];
                xout[ob + (long)v * 64 + nt * 16 + r] = (_Float16)(val > 0.f ? val : 0.f);
            }
        }
}

// ---------------- down2: swapped operands -> coalesced NCDHW fp32 stores ----
__global__ __launch_bounds__(128)
void down2_kernel(const _Float16* __restrict__ xin,  // X4 [20][128][128][64]
                  const _Float16* __restrict__ wt,   // [3][64][64]
                  float* __restrict__ out) {         // [64][9][128][128]
    __shared__ __align__(16) _Float16 lB[3 * 64 * 72];
    const int bid = blockIdx.x;
    const int d2 = bid >> 7;
    const int h = bid & 127;
    const int tid = threadIdx.x;
    const int wv = tid >> 6;
    const int lane = tid & 63;
    const int q = lane >> 4;
    const int r = lane & 15;

    for (int c = tid; c < 3 * 64 * 8; c += 128) {
        int row = c >> 3;
        int part = c & 7;
        *(f16x8*)&lB[row * 72 + part * 8] = *(const f16x8*)&wt[row * 64 + part * 8];
    }
    __syncthreads();

    f32x4 acc[4][4];
    #pragma unroll
    for (int mt = 0; mt < 4; ++mt)
        #pragma unroll
        for (int nt = 0; nt < 4; ++nt) {
            acc[mt][nt][0] = 0.f; acc[mt][nt][1] = 0.f;
            acc[mt][nt][2] = 0.f; acc[mt][nt][3] = 0.f;
        }

    for (int kd = 0; kd < 3; ++kd) {
        long ib = (((long)(2 * d2 + kd) * 128 + h) * 128) * 64;
        #pragma unroll
        for (int kc = 0; kc < 2; ++kc) {
            f16x8 wfr[4], xf[4];
            #pragma unroll
            for (int mt = 0; mt < 4; ++mt)
                wfr[mt] = *(const f16x8*)&lB[(kd * 64 + mt * 16 + r) * 72 + kc * 32 + q * 8];
            #pragma unroll
            for (int nt = 0; nt < 4; ++nt)
                xf[nt] = *(const f16x8*)&xin[ib + (long)(wv * 64 + nt * 16 + r) * 64 + kc * 32 + q * 8];
            #pragma unroll
            for (int mt = 0; mt < 4; ++mt)
                #pragma unroll
                for (int nt = 0; nt < 4; ++nt)
                    acc[mt][nt] = __builtin_amdgcn_mfma_f32_16x16x32_f16(
                        wfr[mt], xf[nt], acc[mt][nt], 0, 0, 0);
        }
    }
    #pragma unroll
    for (int mt = 0; mt < 4; ++mt)
        #pragma unroll
        for (int i = 0; i < 4; ++i) {
            int co = mt * 16 + q * 4 + i;
            #pragma unroll
            for (int nt = 0; nt < 4; ++nt) {
                int v = wv * 64 + nt * 16 + r;
                float val = acc[mt][nt][i];
                out[((long)co * 9 + d2) * 16384 + h * 128 + v] = (val > 0.f ? val : 0.f);
            }
        }
}

// ---------------- launcher ----------------
extern "C" void kernel_launch(void* const* d_in, const int* in_sizes, int n_in,
                              void* d_out, int out_size, void* d_ws, size_t ws_size,
                              hipStream_t stream) {
    (void)in_sizes; (void)n_in; (void)out_size; (void)ws_size;
    const float* feat = (const float*)d_in[0];
    const float* mask = (const float*)d_in[1];
    const float* w0 = (const float*)d_in[2];
    const float* w1 = (const float*)d_in[3];
    const float* w2 = (const float*)d_in[4];
    const float* w3 = (const float*)d_in[5];
    const float* w4 = (const float*)d_in[6];

    char* ws = (char*)d_ws;
    _Float16* X0  = (_Float16*)(ws + OFF_X0);
    _Float16* X1  = (_Float16*)(ws + OFF_X1);
    _Float16* X2  = (_Float16*)(ws + OFF_X2);   // overlays dead X0
    _Float16* X3  = (_Float16*)(ws + OFF_X3);
    _Float16* X4  = (_Float16*)(ws + OFF_X4);   // overlays dead X2
    float*    M1  = (float*)(ws + OFF_M1);
    _Float16* W0f = (_Float16*)(ws + OFF_W0);
    _Float16* W1t = (_Float16*)(ws + OFF_W1);
    _Float16* W2f = (_Float16*)(ws + OFF_W2);
    _Float16* W3f = (_Float16*)(ws + OFF_W3);
    _Float16* W4t = (_Float16*)(ws + OFF_W4);

    prep_w_frag<<<(27*4*2048 + 255) / 256, 256, 0, stream>>>(w0, W0f, 128, 4, 27);
    prep_w_frag<<<(27*2*2048 + 255) / 256, 256, 0, stream>>>(w2, W2f, 64, 2, 27);
    prep_w_frag<<<(27*2*2048 + 255) / 256, 256, 0, stream>>>(w3, W3f, 64, 2, 27);
    prep_w<<<(3*64*64 + 255) / 256, 256, 0, stream>>>(w1, W1t, 64, 64, 3);
    prep_w<<<(3*64*64 + 255) / 256, 256, 0, stream>>>(w4, W4t, 64, 64, 3);
    prep_m1<<<((int)NVOX1 + 255) / 256, 256, 0, stream>>>(mask, M1);
    prep_x0<<<(int)(NVOX0 / 256), 256, 0, stream>>>(feat, mask, X0);

    // conv0: 128->64, 3x3x3 SAME (input mask folded into X0, output mask = mask)
    subm_conv<128><<<41 * 128, 128, 0, stream>>>(X0, mask, W0f, X1, 41);
    // down1
    down1_kernel<<<20 * 128, 128, 0, stream>>>(X1, W1t, X2);
    // subm1a / subm1b
    subm_conv<64><<<20 * 128, 128, 0, stream>>>(X2, M1, W2f, X3, 20);
    subm_conv<64><<<20 * 128, 128, 0, stream>>>(X3, M1, W3f, X4, 20);
    // down2 -> fp32 NCDHW output
    down2_kernel<<<9 * 128, 128, 0, stream>>>(X4, W4t, (float*)d_out);
}